// Round 5
// baseline (1613.843 us; speedup 1.0000x reference)
//
#include <hip/hip_runtime.h>
#include <hip/hip_bf16.h>
#include <stdint.h>

#define NT    204800     // nodes
#define NE    3276800    // edges
#define ED    64         // embed dim
#define NBG   8192       // graphs
#define HID   1600       // 25*64
#define HPAD  1664       // 13*128
#define NB2   800        // dst buckets (d>>8), 256 nodes each
#define BN    256        // nodes per bucket
#define BCAP2 4608       // per-bucket record capacity (mean 4096, +8 sigma)
#define NTILE 100        // src tiles (src>>11), 2048 nodes = 256KB window

typedef float  f32x4  __attribute__((ext_vector_type(4)));
typedef __bf16 bf16x8 __attribute__((ext_vector_type(8)));

__device__ __forceinline__ void async_ld16(const void* g, void* l) {
    __builtin_amdgcn_global_load_lds(
        (__attribute__((address_space(1))) const void*)g,
        (__attribute__((address_space(3))) void*)l, 16, 0, 0);
}

// ---------- init global bucket cursors ----------
__global__ void k_initg(int* __restrict__ gcur) {
    int t = threadIdx.x;
    if (t < NB2) gcur[t] = t * BCAP2;
}

// ---------- pass A: radix-partition edges into 800 dst buckets ----------
// record = (src<<8) | (dst & 255), 4 bytes. Two-phase LDS histogram ->
// one global atomicAdd per (block,bucket) -> direct writes in short runs.
__global__ __launch_bounds__(1024) void k_part(const int* __restrict__ srcv,
                                               const int* __restrict__ dstv,
                                               int* __restrict__ gcur,
                                               unsigned* __restrict__ rec) {
    __shared__ int hist[NB2];
    __shared__ int slot[NB2];
    __shared__ int gofs[NB2];
    const int t = threadIdx.x;
    const int base = blockIdx.x * (NE / 256);   // 12800-edge chunk
    if (t < NB2) { hist[t] = 0; slot[t] = 0; }
    __syncthreads();
    for (int i = base + t; i < base + NE / 256; i += 1024)
        atomicAdd(&hist[dstv[i] >> 8], 1);
    __syncthreads();
    if (t < NB2) gofs[t] = atomicAdd(&gcur[t], hist[t]);
    __syncthreads();
    for (int i = base + t; i < base + NE / 256; i += 1024) {
        int d = dstv[i], s = srcv[i];
        int bb = d >> 8;
        int ls = atomicAdd(&slot[bb], 1);
        int idx = gofs[bb] + ls;
        if (idx < (bb + 1) * BCAP2)   // overflow guard (P ~ 0)
            rec[idx] = ((unsigned)s << 8) | (unsigned)(d & 255);
    }
}

// ---------- pass B: in-bucket counting sort by src-tile + degree/dinv ----------
// Sorting by src>>11 gives all fagg blocks the same src-walk order -> the
// random 128B hb reads develop temporal locality and hit L2 instead of IF$.
__global__ __launch_bounds__(256) void k_sortb(const int* __restrict__ gcur,
                                               unsigned* __restrict__ rec,
                                               float* __restrict__ dinv) {
    __shared__ unsigned rb[BCAP2];
    __shared__ unsigned rs[BCAP2];
    __shared__ int hist[NTILE];
    __shared__ int ofs[NTILE];
    __shared__ int cnt[BN];
    const int t = threadIdx.x;
    const int b = blockIdx.x;
    if (t < NTILE) hist[t] = 0;
    cnt[t] = 0;
    __syncthreads();
    int total = gcur[b] - b * BCAP2;
    if (total > BCAP2) total = BCAP2;
    unsigned* gr = rec + (size_t)b * BCAP2;
    for (int i = t; i < total; i += 256) {
        unsigned r = gr[i];
        rb[i] = r;
        atomicAdd(&hist[r >> 19], 1);   // src>>11
        atomicAdd(&cnt[r & 255], 1);
    }
    __syncthreads();
    if (t == 0) {
        int a = 0;
        for (int i = 0; i < NTILE; ++i) { int h = hist[i]; ofs[i] = a; a += h; }
    }
    __syncthreads();
    for (int i = t; i < total; i += 256) {
        unsigned r = rb[i];
        int p = atomicAdd(&ofs[r >> 19], 1);
        rs[p] = r;
    }
    __syncthreads();
    for (int i = t; i < total; i += 256) gr[i] = rs[i];   // in-place (block-local)
    dinv[b * BN + t] = rsqrtf((float)cnt[t] + 1.f);        // +1 self-loop
}

// ---------- hbs = bf16( (x @ W_conv) * dinv[row] )  (pre-scaled by src norm) ----------
__global__ __launch_bounds__(256) void k_gemm_conv(const float* __restrict__ x,
                                                   const float* __restrict__ Wc,
                                                   const float* __restrict__ dinv,
                                                   __hip_bfloat16* __restrict__ hbs) {
    __shared__ float Ws[64 * 64];
    __shared__ float Xt[64 * 72];   // [k][r], padded
    const int t = threadIdx.x;
    const int row0 = blockIdx.x * 64;
#pragma unroll
    for (int i = 0; i < 4; ++i) {
        int idx = i * 256 + t;                 // float4 units, 0..1023
        ((f32x4*)Ws)[idx] = ((const f32x4*)Wc)[idx];
        int r = idx >> 4, c4 = (idx & 15) << 2;
        f32x4 v = ((const f32x4*)(x + (size_t)row0 * 64))[idx];
        Xt[(c4 + 0) * 72 + r] = v.x;
        Xt[(c4 + 1) * 72 + r] = v.y;
        Xt[(c4 + 2) * 72 + r] = v.z;
        Xt[(c4 + 3) * 72 + r] = v.w;
    }
    __syncthreads();
    const int r0 = (t >> 4) << 2;
    const int c0 = (t & 15) << 2;
    f32x4 acc[4] = {};
#pragma unroll 8
    for (int k = 0; k < 64; ++k) {
        f32x4 xv = *(const f32x4*)&Xt[k * 72 + r0];
        f32x4 wv = *(const f32x4*)&Ws[k * 64 + c0];
        acc[0] += xv.x * wv;
        acc[1] += xv.y * wv;
        acc[2] += xv.z * wv;
        acc[3] += xv.w * wv;
    }
#pragma unroll
    for (int i = 0; i < 4; ++i) {
        int row = row0 + r0 + i;
        float di = dinv[row];
        f32x4 a = acc[i] * di;
        __hip_bfloat16* dst = &hbs[(size_t)row * 64 + c0];
        __hip_bfloat162 p0 = __float22bfloat162_rn(make_float2(a.x, a.y));
        __hip_bfloat162 p1 = __float22bfloat162_rn(make_float2(a.z, a.w));
        *(__hip_bfloat162*)(dst)     = p0;
        *(__hip_bfloat162*)(dst + 2) = p1;
    }
}

// ---------- fused gather-aggregate: LDS fp32 accumulators, zero global atomics ----------
// Hb[d] = bf16( relu( bc + dinv[d] * ( hbs[d] + sum_rec hbs[src] ) ) )
__global__ __launch_bounds__(512) void k_fagg(const int* __restrict__ gcur,
                                              const unsigned* __restrict__ rec,
                                              const float* __restrict__ dinv,
                                              const __hip_bfloat16* __restrict__ hbs,
                                              const float* __restrict__ bc,
                                              __hip_bfloat16* __restrict__ Hb) {
    __shared__ float acc[BN * 64];   // 64 KB
    const int t = threadIdx.x;
    const int wv = t >> 6, lane = t & 63;
    const int b = blockIdx.x;
    const int n0 = b * BN;
    // init with self-loop term (hbs rows, coalesced, 4 bf16 per thread-iter)
    {
        const ushort4* srcp = (const ushort4*)(hbs + (size_t)n0 * 64);
        for (int i = t; i < BN * 16; i += 512) {
            ushort4 v = srcp[i];
            float* a = &acc[i * 4];
            a[0] = __bfloat162float(*(__hip_bfloat16*)&v.x);
            a[1] = __bfloat162float(*(__hip_bfloat16*)&v.y);
            a[2] = __bfloat162float(*(__hip_bfloat16*)&v.z);
            a[3] = __bfloat162float(*(__hip_bfloat16*)&v.w);
        }
    }
    __syncthreads();
    int total = gcur[b] - b * BCAP2;
    if (total > BCAP2) total = BCAP2;
    const unsigned* rb = rec + (size_t)b * BCAP2;
    for (int base = wv * 64; base < total; base += 512) {
        int nav = total - base; if (nav > 64) nav = 64;
        unsigned r = (lane < nav) ? rb[base + lane] : 0;
        int j = 0;
        for (; j + 8 <= nav; j += 8) {
            unsigned r0 = __builtin_amdgcn_readlane(r, j + 0);
            unsigned r1 = __builtin_amdgcn_readlane(r, j + 1);
            unsigned r2 = __builtin_amdgcn_readlane(r, j + 2);
            unsigned r3 = __builtin_amdgcn_readlane(r, j + 3);
            unsigned r4 = __builtin_amdgcn_readlane(r, j + 4);
            unsigned r5 = __builtin_amdgcn_readlane(r, j + 5);
            unsigned r6 = __builtin_amdgcn_readlane(r, j + 6);
            unsigned r7 = __builtin_amdgcn_readlane(r, j + 7);
            float h0 = __bfloat162float(hbs[((size_t)(r0 >> 8)) * 64 + lane]);
            float h1 = __bfloat162float(hbs[((size_t)(r1 >> 8)) * 64 + lane]);
            float h2 = __bfloat162float(hbs[((size_t)(r2 >> 8)) * 64 + lane]);
            float h3 = __bfloat162float(hbs[((size_t)(r3 >> 8)) * 64 + lane]);
            float h4 = __bfloat162float(hbs[((size_t)(r4 >> 8)) * 64 + lane]);
            float h5 = __bfloat162float(hbs[((size_t)(r5 >> 8)) * 64 + lane]);
            float h6 = __bfloat162float(hbs[((size_t)(r6 >> 8)) * 64 + lane]);
            float h7 = __bfloat162float(hbs[((size_t)(r7 >> 8)) * 64 + lane]);
            atomicAdd(&acc[(r0 & 255) * 64 + lane], h0);
            atomicAdd(&acc[(r1 & 255) * 64 + lane], h1);
            atomicAdd(&acc[(r2 & 255) * 64 + lane], h2);
            atomicAdd(&acc[(r3 & 255) * 64 + lane], h3);
            atomicAdd(&acc[(r4 & 255) * 64 + lane], h4);
            atomicAdd(&acc[(r5 & 255) * 64 + lane], h5);
            atomicAdd(&acc[(r6 & 255) * 64 + lane], h6);
            atomicAdd(&acc[(r7 & 255) * 64 + lane], h7);
        }
        for (; j < nav; ++j) {
            unsigned rj = __builtin_amdgcn_readlane(r, j);
            float hv = __bfloat162float(hbs[((size_t)(rj >> 8)) * 64 + lane]);
            atomicAdd(&acc[(rj & 255) * 64 + lane], hv);
        }
    }
    __syncthreads();
    // epilogue: bias + dst-norm scale + relu + bf16, 2 ch per thread
    for (int i = t; i < BN * 32; i += 512) {
        int rel = i >> 5, ch2 = (i & 31) * 2;
        float di = dinv[n0 + rel];
        float v0 = bc[ch2]     + di * acc[rel * 64 + ch2];
        float v1 = bc[ch2 + 1] + di * acc[rel * 64 + ch2 + 1];
        __hip_bfloat162 p = __float22bfloat162_rn(make_float2(fmaxf(v0, 0.f), fmaxf(v1, 0.f)));
        *(__hip_bfloat162*)&Hb[(size_t)(n0 + rel) * 64 + ch2] = p;
    }
}

// ---------- W1 -> bf16, transposed [HPAD][HID] ----------
__global__ void k_convW1(const float* __restrict__ W1, __hip_bfloat16* __restrict__ Bt) {
    __shared__ float tile[64][65];
    const int t = threadIdx.x;
    const int k0 = blockIdx.x * 64;   // 25 tiles
    const int n0 = blockIdx.y * 64;   // 26 tiles (pad zero)
#pragma unroll
    for (int i = 0; i < 16; ++i) {
        int lin = i * 256 + t;
        int r = lin >> 6, c = lin & 63;
        int n = n0 + c;
        tile[r][c] = (n < HID) ? W1[(size_t)(k0 + r) * HID + n] : 0.f;
    }
    __syncthreads();
#pragma unroll
    for (int i = 0; i < 16; ++i) {
        int lin = i * 256 + t;
        int nn = lin >> 6, kk = lin & 63;
        Bt[(size_t)(n0 + nn) * HID + k0 + kk] = __float2bfloat16(tile[kk][nn]);
    }
}

// ---------- h2 = relu(Hb @ W1 + b1)  (bf16 MFMA, 128x128 tile, BK=32) ----------
__global__ __launch_bounds__(256) void k_gemm1(const __hip_bfloat16* __restrict__ A,
                                               const __hip_bfloat16* __restrict__ Bt,
                                               const float* __restrict__ b1,
                                               __hip_bfloat16* __restrict__ h2) {
    __shared__ unsigned short As[128 * 32];
    __shared__ unsigned short Bs[128 * 32];
    const int t = threadIdx.x;
    const int lane = t & 63;
    const int wave = t >> 6;
    const int bm0 = blockIdx.x * 128;
    const int bn0 = blockIdx.y * 128;
    const int wm = (wave >> 1) * 64;
    const int wn = (wave & 1) * 64;
    const int fr = lane & 15;
    const int fq = lane >> 4;
    const int sr = t >> 2;
    const int sc = (t & 3) * 8;
    const __hip_bfloat16* ga0 = A + (size_t)(bm0 + sr) * HID + sc;
    const __hip_bfloat16* ga1 = A + (size_t)(bm0 + 64 + sr) * HID + sc;
    const __hip_bfloat16* gb0 = Bt + (size_t)(bn0 + sr) * HID + sc;
    const __hip_bfloat16* gb1 = Bt + (size_t)(bn0 + 64 + sr) * HID + sc;
    unsigned short* lA0 = &As[t * 8];
    unsigned short* lA1 = &As[(256 + t) * 8];
    unsigned short* lB0 = &Bs[t * 8];
    unsigned short* lB1 = &Bs[(256 + t) * 8];
    const unsigned short* fa0 = &As[(wm + fr) * 32 + fq * 8];
    const unsigned short* fb0 = &Bs[(wn + fr) * 32 + fq * 8];
    f32x4 acc[4][4] = {};
    for (int k0 = 0; k0 < HID; k0 += 32) {
        async_ld16(ga0, lA0); async_ld16(ga1, lA1);
        async_ld16(gb0, lB0); async_ld16(gb1, lB1);
        ga0 += 32; ga1 += 32; gb0 += 32; gb1 += 32;
        __syncthreads();
        bf16x8 av[4], bv[4];
#pragma unroll
        for (int i = 0; i < 4; ++i) av[i] = *(const bf16x8*)(fa0 + i * 16 * 32);
#pragma unroll
        for (int j = 0; j < 4; ++j) bv[j] = *(const bf16x8*)(fb0 + j * 16 * 32);
#pragma unroll
        for (int i = 0; i < 4; ++i)
#pragma unroll
            for (int j = 0; j < 4; ++j)
                acc[i][j] = __builtin_amdgcn_mfma_f32_16x16x32_bf16(av[i], bv[j], acc[i][j], 0, 0, 0);
        __syncthreads();
    }
#pragma unroll
    for (int j = 0; j < 4; ++j) {
        int n = bn0 + wn + j * 16 + fr;
        if (n < HID) {
            float bias = b1[n];
#pragma unroll
            for (int i = 0; i < 4; ++i) {
#pragma unroll
                for (int r = 0; r < 4; ++r) {
                    int m = bm0 + wm + i * 16 + fq * 4 + r;
                    float v = acc[i][j][r] + bias;
                    h2[(size_t)m * HID + n] = __float2bfloat16(fmaxf(v, 0.f));
                }
            }
        }
    }
}

// ---------- logits + softmax (one wave per graph) ----------
__global__ void k_head(const __hip_bfloat16* __restrict__ h2, const float* __restrict__ W2,
                       const float* __restrict__ b2, float* __restrict__ out) {
    int g = blockIdx.x * 4 + (threadIdx.x >> 6);
    int lane = threadIdx.x & 63;
    const __hip_bfloat16* row = h2 + (size_t)g * HID;
    float a0 = 0.f, a1 = 0.f;
#pragma unroll
    for (int i = 0; i < 25; ++i) {
        int k = i * 64 + lane;
        float hv = __bfloat162float(row[k]);
        float2 w = ((const float2*)W2)[k];
        a0 += hv * w.x;
        a1 += hv * w.y;
    }
#pragma unroll
    for (int off = 32; off > 0; off >>= 1) {
        a0 += __shfl_down(a0, off, 64);
        a1 += __shfl_down(a1, off, 64);
    }
    if (lane == 0) {
        float l0 = a0 + b2[0], l1 = a1 + b2[1];
        float mx = fmaxf(l0, l1);
        float e0 = expf(l0 - mx), e1 = expf(l1 - mx);
        float s = e0 + e1;
        out[2 * g]     = e0 / s;
        out[2 * g + 1] = e1 / s;
    }
}

extern "C" void kernel_launch(void* const* d_in, const int* in_sizes, int n_in,
                              void* d_out, int out_size, void* d_ws, size_t ws_size,
                              hipStream_t stream) {
    const float* x  = (const float*)d_in[0];
    const int*   ei = (const int*)d_in[1];
    // d_in[2] = batch (unused; reshape handles grouping)
    const float* Wc = (const float*)d_in[3];
    const float* bc = (const float*)d_in[4];
    const float* W1 = (const float*)d_in[5];
    const float* b1 = (const float*)d_in[6];
    const float* W2 = (const float*)d_in[7];
    const float* b2 = (const float*)d_in[8];
    float* out = (float*)d_out;

    const int* srcv = ei;
    const int* dstv = ei + NE;

    // workspace layout (bytes):
    //   dinv : [0,        819200)
    //   gcur : [819200,   822400)
    //   rec  : [822400,   15568000)    unsigned[NB2*BCAP2]
    //   hbs  : [15568000, 41782400)    bf16 pre-scaled conv out; dead after k_fagg
    //     h2 : [15568000, 41782400)    bf16, overlays dead hbs
    //   Hb   : [41782400, 67996800)    bf16 gather out
    //   Bt   : [67996800, 73321600)    bf16 W1^T padded
    char* ws = (char*)d_ws;
    float*    dinv = (float*)ws;
    int*      gcur = (int*)(ws + 819200);
    unsigned* rec  = (unsigned*)(ws + 822400);
    __hip_bfloat16* hbs = (__hip_bfloat16*)(ws + 15568000);
    __hip_bfloat16* h2  = (__hip_bfloat16*)(ws + 15568000);
    __hip_bfloat16* Hb  = (__hip_bfloat16*)(ws + 41782400);
    __hip_bfloat16* Bt  = (__hip_bfloat16*)(ws + 67996800);

    k_initg    <<<1, 1024, 0, stream>>>(gcur);
    k_part     <<<256, 1024, 0, stream>>>(srcv, dstv, gcur, rec);
    k_sortb    <<<NB2, 256, 0, stream>>>(gcur, rec, dinv);
    k_gemm_conv<<<NT / 64, 256, 0, stream>>>(x, Wc, dinv, hbs);
    k_fagg     <<<NB2, 512, 0, stream>>>(gcur, rec, dinv, hbs, bc, Hb);
    k_convW1   <<<dim3(HID / 64, HPAD / 64), 256, 0, stream>>>(W1, Bt);
    k_gemm1    <<<dim3(NBG / 128, HPAD / 128), 256, 0, stream>>>(Hb, Bt, b1, h2);
    k_head     <<<NBG / 4, 256, 0, stream>>>(h2, W2, b2, out);
}

// Round 6
// 463.019 us; speedup vs baseline: 3.4855x; 3.4855x over previous
//
#include <hip/hip_runtime.h>
#include <hip/hip_bf16.h>
#include <stdint.h>

#define NT   204800      // nodes
#define NE   3276800     // edges
#define ED   64          // embed dim
#define NBG  8192        // graphs
#define HID  1600        // 25*64
#define HPAD 1664        // 13*128
#define CAP  56          // per-node bucket capacity (max Poisson(16) indegree ~38)
#define NBKT 100         // dst>>11 -> 100 buckets of 2048 nodes
#define BCAP 36864       // per-bucket record capacity (mean 32768)

typedef float  f32x4  __attribute__((ext_vector_type(4)));
typedef __bf16 bf16x8 __attribute__((ext_vector_type(8)));

__device__ __forceinline__ void async_ld16(const void* g, void* l) {
    __builtin_amdgcn_global_load_lds(
        (__attribute__((address_space(1))) const void*)g,
        (__attribute__((address_space(3))) void*)l, 16, 0, 0);
}

// ---------- init global bucket cursors to fixed bases ----------
__global__ void k_initg(int* __restrict__ gcur) {
    int t = threadIdx.x;
    if (t < NBKT) gcur[t] = t * BCAP;
}

// ---------- pass A: radix-partition edges into 100 dst-range buckets ----------
__global__ __launch_bounds__(256) void k_part(const int* __restrict__ srcv,
                                              const int* __restrict__ dstv,
                                              int* __restrict__ gcur,
                                              uint2* __restrict__ rec) {
    __shared__ int hist[NBKT];
    __shared__ int slot[NBKT];
    __shared__ int gofs[NBKT];
    const int t = threadIdx.x;
    const int base = blockIdx.x * (NE / 256);   // 12800-edge chunk
    if (t < NBKT) { hist[t] = 0; slot[t] = 0; }
    __syncthreads();
    for (int j = 0; j < 50; ++j) {
        int d = dstv[base + j * 256 + t];
        atomicAdd(&hist[d >> 11], 1);
    }
    __syncthreads();
    if (t < NBKT) gofs[t] = atomicAdd(&gcur[t], hist[t]);
    __syncthreads();
    for (int j = 0; j < 50; ++j) {
        int i = base + j * 256 + t;
        int d = dstv[i];
        int s = srcv[i];
        int b = d >> 11;
        int ls = atomicAdd(&slot[b], 1);
        int idx = gofs[b] + ls;
        if (idx < (b + 1) * BCAP)   // overflow guard (P ~ 0)
            rec[idx] = make_uint2((unsigned)s, (unsigned)d);
    }
}

// ---------- pass B: bucket-local CSR fill, LDS *int* counters ----------
__global__ __launch_bounds__(256) void k_fillb(const int* __restrict__ gcur,
                                               const uint2* __restrict__ rec,
                                               int* __restrict__ cur,
                                               int* __restrict__ csr) {
    __shared__ int cnt[1024];
    const int t = threadIdx.x;
    const int b = blockIdx.x >> 1;
    const int n0 = b * 2048 + (blockIdx.x & 1) * 1024;
    for (int i = t; i < 1024; i += 256) cnt[i] = 0;
    __syncthreads();
    const int bstart = b * BCAP;
    int bcnt = gcur[b] - bstart;
    bcnt = (bcnt > BCAP) ? BCAP : bcnt;
    for (int idx = t; idx < bcnt; idx += 256) {
        uint2 r = rec[bstart + idx];
        int d = (int)r.y;
        unsigned rel = (unsigned)(d - n0);
        if (rel < 1024u) {
            int ls = atomicAdd(&cnt[rel], 1);
            if (ls < CAP) csr[(size_t)d * CAP + ls] = (int)r.x;
        }
    }
    __syncthreads();
    for (int i = t; i < 1024; i += 256) cur[n0 + i] = cnt[i];
}

// ---------- dinv from counts ----------
__global__ void k_dinv(const int* __restrict__ cur, float* __restrict__ dinv) {
    int i = blockIdx.x * 256 + threadIdx.x;
    dinv[i] = rsqrtf((float)cur[i] + 1.f);   // +1 self-loop
}

// ---------- hbs = bf16( (x @ W_conv) * dinv[row] )  (pre-scaled by src norm) ----------
__global__ __launch_bounds__(256) void k_gemm_conv(const float* __restrict__ x,
                                                   const float* __restrict__ Wc,
                                                   const float* __restrict__ dinv,
                                                   __hip_bfloat16* __restrict__ hbs) {
    __shared__ float Ws[64 * 64];
    __shared__ float Xt[64 * 72];   // [k][r], padded
    const int t = threadIdx.x;
    const int row0 = blockIdx.x * 64;
#pragma unroll
    for (int i = 0; i < 4; ++i) {
        int idx = i * 256 + t;                 // float4 units, 0..1023
        ((f32x4*)Ws)[idx] = ((const f32x4*)Wc)[idx];
        int r = idx >> 4, c4 = (idx & 15) << 2;
        f32x4 v = ((const f32x4*)(x + (size_t)row0 * 64))[idx];
        Xt[(c4 + 0) * 72 + r] = v.x;
        Xt[(c4 + 1) * 72 + r] = v.y;
        Xt[(c4 + 2) * 72 + r] = v.z;
        Xt[(c4 + 3) * 72 + r] = v.w;
    }
    __syncthreads();
    const int r0 = (t >> 4) << 2;
    const int c0 = (t & 15) << 2;
    f32x4 acc[4] = {};
#pragma unroll 8
    for (int k = 0; k < 64; ++k) {
        f32x4 xv = *(const f32x4*)&Xt[k * 72 + r0];
        f32x4 wv = *(const f32x4*)&Ws[k * 64 + c0];
        acc[0] += xv.x * wv;
        acc[1] += xv.y * wv;
        acc[2] += xv.z * wv;
        acc[3] += xv.w * wv;
    }
#pragma unroll
    for (int i = 0; i < 4; ++i) {
        int row = row0 + r0 + i;
        float di = dinv[row];
        f32x4 a = acc[i] * di;
        __hip_bfloat16* dst = &hbs[(size_t)row * 64 + c0];
        __hip_bfloat162 p0 = __float22bfloat162_rn(make_float2(a.x, a.y));
        __hip_bfloat162 p1 = __float22bfloat162_rn(make_float2(a.z, a.w));
        *(__hip_bfloat162*)(dst)     = p0;
        *(__hip_bfloat162*)(dst + 2) = p1;
    }
}

// ---------- gather: one wave per node, lane = channel, 8 rows in flight ----------
// Hb[d] = bf16( relu( bc + dinv[d] * ( hbs[d] + sum_src hbs[src] ) ) )
__global__ __launch_bounds__(256) void k_gather(const int* __restrict__ cur,
                                                const int* __restrict__ csr,
                                                const float* __restrict__ dinv,
                                                const __hip_bfloat16* __restrict__ hbs,
                                                const float* __restrict__ bc,
                                                __hip_bfloat16* __restrict__ Hb) {
    const int lane = threadIdx.x & 63;
    const int d = blockIdx.x * 4 + (threadIdx.x >> 6);
    const float di = dinv[d];
    int cn = cur[d];
    cn = (cn > CAP) ? CAP : cn;
    // wave loads its edge list in one coalesced read, then shfl-broadcasts
    int me = (lane < cn) ? csr[(size_t)d * CAP + lane] : 0;
    float acc = __bfloat162float(hbs[(size_t)d * ED + lane]);   // self-loop term
    int e = 0;
    for (; e + 8 <= cn; e += 8) {
        int s0 = __shfl(me, e,     64);
        int s1 = __shfl(me, e + 1, 64);
        int s2 = __shfl(me, e + 2, 64);
        int s3 = __shfl(me, e + 3, 64);
        int s4 = __shfl(me, e + 4, 64);
        int s5 = __shfl(me, e + 5, 64);
        int s6 = __shfl(me, e + 6, 64);
        int s7 = __shfl(me, e + 7, 64);
        float h0 = __bfloat162float(hbs[(size_t)s0 * ED + lane]);
        float h1 = __bfloat162float(hbs[(size_t)s1 * ED + lane]);
        float h2 = __bfloat162float(hbs[(size_t)s2 * ED + lane]);
        float h3 = __bfloat162float(hbs[(size_t)s3 * ED + lane]);
        float h4 = __bfloat162float(hbs[(size_t)s4 * ED + lane]);
        float h5 = __bfloat162float(hbs[(size_t)s5 * ED + lane]);
        float h6 = __bfloat162float(hbs[(size_t)s6 * ED + lane]);
        float h7 = __bfloat162float(hbs[(size_t)s7 * ED + lane]);
        acc += ((h0 + h1) + (h2 + h3)) + ((h4 + h5) + (h6 + h7));
    }
    for (; e < cn; ++e) {
        int s = __shfl(me, e, 64);
        acc += __bfloat162float(hbs[(size_t)s * ED + lane]);
    }
    Hb[(size_t)d * ED + lane] = __float2bfloat16(fmaxf(bc[lane] + di * acc, 0.f));
}

// ---------- W1 -> bf16, transposed [HPAD][HID] ----------
__global__ void k_convW1(const float* __restrict__ W1, __hip_bfloat16* __restrict__ Bt) {
    __shared__ float tile[64][65];
    const int t = threadIdx.x;
    const int k0 = blockIdx.x * 64;   // 25 tiles
    const int n0 = blockIdx.y * 64;   // 26 tiles (pad zero)
#pragma unroll
    for (int i = 0; i < 16; ++i) {
        int lin = i * 256 + t;
        int r = lin >> 6, c = lin & 63;
        int n = n0 + c;
        tile[r][c] = (n < HID) ? W1[(size_t)(k0 + r) * HID + n] : 0.f;
    }
    __syncthreads();
#pragma unroll
    for (int i = 0; i < 16; ++i) {
        int lin = i * 256 + t;
        int nn = lin >> 6, kk = lin & 63;
        Bt[(size_t)(n0 + nn) * HID + k0 + kk] = __float2bfloat16(tile[kk][nn]);
    }
}

// ---------- h2 = relu(Hb @ W1 + b1)  (bf16 MFMA, 128x128 tile, BK=32) ----------
__global__ __launch_bounds__(256) void k_gemm1(const __hip_bfloat16* __restrict__ A,
                                               const __hip_bfloat16* __restrict__ Bt,
                                               const float* __restrict__ b1,
                                               __hip_bfloat16* __restrict__ h2) {
    __shared__ unsigned short As[128 * 32];
    __shared__ unsigned short Bs[128 * 32];
    const int t = threadIdx.x;
    const int lane = t & 63;
    const int wave = t >> 6;
    const int bm0 = blockIdx.x * 128;
    const int bn0 = blockIdx.y * 128;
    const int wm = (wave >> 1) * 64;
    const int wn = (wave & 1) * 64;
    const int fr = lane & 15;
    const int fq = lane >> 4;
    const int sr = t >> 2;
    const int sc = (t & 3) * 8;
    const __hip_bfloat16* ga0 = A + (size_t)(bm0 + sr) * HID + sc;
    const __hip_bfloat16* ga1 = A + (size_t)(bm0 + 64 + sr) * HID + sc;
    const __hip_bfloat16* gb0 = Bt + (size_t)(bn0 + sr) * HID + sc;
    const __hip_bfloat16* gb1 = Bt + (size_t)(bn0 + 64 + sr) * HID + sc;
    unsigned short* lA0 = &As[t * 8];
    unsigned short* lA1 = &As[(256 + t) * 8];
    unsigned short* lB0 = &Bs[t * 8];
    unsigned short* lB1 = &Bs[(256 + t) * 8];
    const unsigned short* fa0 = &As[(wm + fr) * 32 + fq * 8];
    const unsigned short* fb0 = &Bs[(wn + fr) * 32 + fq * 8];
    f32x4 acc[4][4] = {};
    for (int k0 = 0; k0 < HID; k0 += 32) {
        async_ld16(ga0, lA0); async_ld16(ga1, lA1);
        async_ld16(gb0, lB0); async_ld16(gb1, lB1);
        ga0 += 32; ga1 += 32; gb0 += 32; gb1 += 32;
        __syncthreads();
        bf16x8 av[4], bv[4];
#pragma unroll
        for (int i = 0; i < 4; ++i) av[i] = *(const bf16x8*)(fa0 + i * 16 * 32);
#pragma unroll
        for (int j = 0; j < 4; ++j) bv[j] = *(const bf16x8*)(fb0 + j * 16 * 32);
#pragma unroll
        for (int i = 0; i < 4; ++i)
#pragma unroll
            for (int j = 0; j < 4; ++j)
                acc[i][j] = __builtin_amdgcn_mfma_f32_16x16x32_bf16(av[i], bv[j], acc[i][j], 0, 0, 0);
        __syncthreads();
    }
#pragma unroll
    for (int j = 0; j < 4; ++j) {
        int n = bn0 + wn + j * 16 + fr;
        if (n < HID) {
            float bias = b1[n];
#pragma unroll
            for (int i = 0; i < 4; ++i) {
#pragma unroll
                for (int r = 0; r < 4; ++r) {
                    int m = bm0 + wm + i * 16 + fq * 4 + r;
                    float v = acc[i][j][r] + bias;
                    h2[(size_t)m * HID + n] = __float2bfloat16(fmaxf(v, 0.f));
                }
            }
        }
    }
}

// ---------- logits + softmax (one wave per graph) ----------
__global__ void k_head(const __hip_bfloat16* __restrict__ h2, const float* __restrict__ W2,
                       const float* __restrict__ b2, float* __restrict__ out) {
    int g = blockIdx.x * 4 + (threadIdx.x >> 6);
    int lane = threadIdx.x & 63;
    const __hip_bfloat16* row = h2 + (size_t)g * HID;
    float a0 = 0.f, a1 = 0.f;
#pragma unroll
    for (int i = 0; i < 25; ++i) {
        int k = i * 64 + lane;
        float hv = __bfloat162float(row[k]);
        float2 w = ((const float2*)W2)[k];
        a0 += hv * w.x;
        a1 += hv * w.y;
    }
#pragma unroll
    for (int off = 32; off > 0; off >>= 1) {
        a0 += __shfl_down(a0, off, 64);
        a1 += __shfl_down(a1, off, 64);
    }
    if (lane == 0) {
        float l0 = a0 + b2[0], l1 = a1 + b2[1];
        float mx = fmaxf(l0, l1);
        float e0 = expf(l0 - mx), e1 = expf(l1 - mx);
        float s = e0 + e1;
        out[2 * g]     = e0 / s;
        out[2 * g + 1] = e1 / s;
    }
}

extern "C" void kernel_launch(void* const* d_in, const int* in_sizes, int n_in,
                              void* d_out, int out_size, void* d_ws, size_t ws_size,
                              hipStream_t stream) {
    const float* x  = (const float*)d_in[0];
    const int*   ei = (const int*)d_in[1];
    // d_in[2] = batch (unused; reshape handles grouping)
    const float* Wc = (const float*)d_in[3];
    const float* bc = (const float*)d_in[4];
    const float* W1 = (const float*)d_in[5];
    const float* b1 = (const float*)d_in[6];
    const float* W2 = (const float*)d_in[7];
    const float* b2 = (const float*)d_in[8];
    float* out = (float*)d_out;

    const int* srcv = ei;
    const int* dstv = ei + NE;

    // workspace layout (bytes):
    //   cur  : [0,         819200)
    //   dinv : [819200,    1638400)
    //   gcur : [1638400,   1642496)
    //   csr  : [1642496,   47517696)    int[NT*CAP]
    //   rec  : [47517696,  77008896)    uint2[NBKT*BCAP]; dead after k_fillb
    //     hbs: [47517696,  73732096)    bf16 pre-scaled conv out, overlays dead rec
    //     h2 : [47517696,  73732096)    bf16, overlays dead hbs
    //   Hb   : [77008896,  103223296)   bf16 gather out
    //   Bt   : [103223296, 108548096)   bf16 W1^T padded
    char* ws = (char*)d_ws;
    int*   cur  = (int*)ws;
    float* dinv = (float*)(ws + 819200);
    int*   gcur = (int*)(ws + 1638400);
    int*   csr  = (int*)(ws + 1642496);
    uint2* rec  = (uint2*)(ws + 47517696);
    __hip_bfloat16* hbs = (__hip_bfloat16*)(ws + 47517696);
    __hip_bfloat16* h2  = (__hip_bfloat16*)(ws + 47517696);
    __hip_bfloat16* Hb  = (__hip_bfloat16*)(ws + 77008896);
    __hip_bfloat16* Bt  = (__hip_bfloat16*)(ws + 103223296);

    k_initg    <<<1, 128, 0, stream>>>(gcur);
    k_part     <<<256, 256, 0, stream>>>(srcv, dstv, gcur, rec);
    k_fillb    <<<2 * NBKT, 256, 0, stream>>>(gcur, rec, cur, csr);
    k_dinv     <<<NT / 256, 256, 0, stream>>>(cur, dinv);
    k_gemm_conv<<<NT / 64, 256, 0, stream>>>(x, Wc, dinv, hbs);
    k_gather   <<<NT / 4, 256, 0, stream>>>(cur, csr, dinv, hbs, bc, Hb);
    k_convW1   <<<dim3(HID / 64, HPAD / 64), 256, 0, stream>>>(W1, Bt);
    k_gemm1    <<<dim3(NBG / 128, HPAD / 128), 256, 0, stream>>>(Hb, Bt, b1, h2);
    k_head     <<<NBG / 4, 256, 0, stream>>>(h2, W2, b2, out);
}